// Round 1
// baseline (412.296 us; speedup 1.0000x reference)
//
#include <hip/hip_runtime.h>
#include <hip/hip_bf16.h>

typedef unsigned int u32;
typedef unsigned short u16;

#define NLOC 8192      // B*HWC
#define CDIM 512
#define LCTX 32
#define NH   8
#define DH   64

__device__ __forceinline__ float bl(u32 u){ return __uint_as_float(u << 16); }
__device__ __forceinline__ float bh(u32 u){ return __uint_as_float(u & 0xffff0000u); }
__device__ __forceinline__ u16 f2b(float f){
  u32 u = __float_as_uint(f);
  return (u16)((u + 0x7fffu + ((u >> 16) & 1u)) >> 16);
}
__device__ __forceinline__ u32 pk2(float a, float b){
  return (u32)f2b(a) | ((u32)f2b(b) << 16);
}

// K0: weights -> bf16. kwb[o][c] = k_w[o][c]; vwt[c][o] = v_w[o][c] (transposed).
__global__ __launch_bounds__(256) void k0_prep(const float* __restrict__ kw,
                                               const float* __restrict__ vw,
                                               u16* __restrict__ kwb,
                                               u16* __restrict__ vwt){
  int i = blockIdx.x * 256 + threadIdx.x;      // 262144 total
  int o = i >> 9, c = i & 511;
  kwb[i] = f2b(kw[i]);
  vwt[c * 512 + o] = f2b(vw[i]);
}

// K1: LayerNorm + kq[t,h,c] = sum_d qln[t,h*64+d] * k_w[h*64+d,c].  32 locations/block.
__global__ __launch_bounds__(256) void k1_lnkq(const float* __restrict__ q,
                                               const float* __restrict__ lng,
                                               const float* __restrict__ lnb,
                                               const u16* __restrict__ kwb,
                                               u16* __restrict__ kqw,   // [local_bn][8][512] bf16
                                               int base){
  __shared__ u16 qT[512 * 32];                 // [o][t], 32KB, transposed for b128 reads
  int tid = threadIdx.x;
  {
    int t = tid >> 3, sub = tid & 7;
    long bn = (long)base + blockIdx.x * 32 + t;
    const float* qr = q + bn * 512;
    float xv[64];
    float s = 0.f, s2 = 0.f;
#pragma unroll
    for (int k = 0; k < 64; k++){ float v = qr[sub + 8 * k]; xv[k] = v; s += v; s2 += v * v; }
    s  += __shfl_xor(s, 1);  s2 += __shfl_xor(s2, 1);
    s  += __shfl_xor(s, 2);  s2 += __shfl_xor(s2, 2);
    s  += __shfl_xor(s, 4);  s2 += __shfl_xor(s2, 4);
    float mu = s * (1.f / 512.f);
    float rstd = rsqrtf(s2 * (1.f / 512.f) - mu * mu + 1e-5f);
#pragma unroll
    for (int k = 0; k < 64; k++){
      int c = sub + 8 * k;
      float v = (xv[k] - mu) * rstd * lng[c] + lnb[c];
      qT[c * 32 + t] = f2b(v);
    }
  }
  __syncthreads();
  int h = tid >> 5, tg = (tid >> 3) & 3, cg = tid & 7;
  for (int co = 0; co < 8; co++){
    float acc[8][8];
#pragma unroll
    for (int i = 0; i < 8; i++)
#pragma unroll
      for (int j = 0; j < 8; j++) acc[i][j] = 0.f;
    for (int d = 0; d < 64; d++){
      int o = h * 64 + d;
      uint4 qv = *(const uint4*)&qT[o * 32 + tg * 8];
      uint4 wv = *(const uint4*)&kwb[o * 512 + co * 64 + cg * 8];
      float qf[8] = { bl(qv.x), bh(qv.x), bl(qv.y), bh(qv.y), bl(qv.z), bh(qv.z), bl(qv.w), bh(qv.w) };
      float wf[8] = { bl(wv.x), bh(wv.x), bl(wv.y), bh(wv.y), bl(wv.z), bh(wv.z), bl(wv.w), bh(wv.w) };
#pragma unroll
      for (int i = 0; i < 8; i++)
#pragma unroll
        for (int j = 0; j < 8; j++) acc[i][j] += qf[i] * wf[j];
    }
#pragma unroll
    for (int i = 0; i < 8; i++){
      long lbn = (long)blockIdx.x * 32 + tg * 8 + i;
      uint4 st;
      st.x = pk2(acc[i][0], acc[i][1]); st.y = pk2(acc[i][2], acc[i][3]);
      st.z = pk2(acc[i][4], acc[i][5]); st.w = pk2(acc[i][6], acc[i][7]);
      *(uint4*)&kqw[(lbn * 8 + h) * 512 + co * 64 + cg * 8] = st;
    }
  }
}

// K2: per-location attention core. Reads kq, writes wctx IN PLACE over kq region.
__global__ __launch_bounds__(256) void k2_attn(const float* __restrict__ ctx,
                                               u16* __restrict__ kqw,  // in: kq, out: wctx
                                               int base){
  __shared__ u16 ctxs[32 * 520];               // [l][c] bf16, pitch 520 (bank-clean)
  __shared__ float kqs[8 * 516];               // [h][c] f32, pitch 516
  __shared__ __align__(16) float wls[32][8];   // softmax weights [l][h]
  __shared__ float rmx[4][8], rsm[4][8];
  int tid = threadIdx.x;
  long bn = (long)base + blockIdx.x;
  // stage ctx -> bf16 LDS
  const float4* cp = (const float4*)(ctx + bn * (32 * 512));
#pragma unroll
  for (int i = 0; i < 16; i++){
    float4 v = cp[i * 256 + tid];
    int e0 = (i * 256 + tid) * 4;
    int l = e0 >> 9, col = e0 & 511;
    uint2 pk; pk.x = pk2(v.x, v.y); pk.y = pk2(v.z, v.w);
    *(uint2*)&ctxs[l * 520 + col] = pk;
  }
  // stage kq -> f32 LDS
  const u32* kqp = (const u32*)(kqw + (long)blockIdx.x * 4096);
#pragma unroll
  for (int r = 0; r < 8; r++){
    int m = r * 256 + tid;
    u32 u = kqp[m];
    int hh = m >> 8, cc = (m & 255) << 1;
    float2 f; f.x = bl(u); f.y = bh(u);
    *(float2*)&kqs[hh * 516 + cc] = f;
  }
  __syncthreads();
  // scores: thread (l = tid>>3, h = tid&7)
  int l = tid >> 3, h = tid & 7;
  float s0 = 0.f, s1 = 0.f, s2 = 0.f, s3 = 0.f;
#pragma unroll 8
  for (int cq = 0; cq < 128; cq++){
    uint2 cv = *(const uint2*)&ctxs[l * 520 + cq * 4];
    float4 kv = *(const float4*)&kqs[h * 516 + cq * 4];
    s0 += bl(cv.x) * kv.x; s1 += bh(cv.x) * kv.y;
    s2 += bl(cv.y) * kv.z; s3 += bh(cv.y) * kv.w;
  }
  float s = (s0 + s1) + (s2 + s3);
  // softmax over l (per h): in-wave over 8 l, then cross-wave via LDS
  float mx = s;
  mx = fmaxf(mx, __shfl_xor(mx, 8));
  mx = fmaxf(mx, __shfl_xor(mx, 16));
  mx = fmaxf(mx, __shfl_xor(mx, 32));
  int wv = tid >> 6;
  if ((tid & 63) < 8) rmx[wv][h] = mx;
  __syncthreads();
  mx = fmaxf(fmaxf(rmx[0][h], rmx[1][h]), fmaxf(rmx[2][h], rmx[3][h]));
  float e = __expf(s - mx);
  float sm = e;
  sm += __shfl_xor(sm, 8);
  sm += __shfl_xor(sm, 16);
  sm += __shfl_xor(sm, 32);
  if ((tid & 63) < 8) rsm[wv][h] = sm;
  __syncthreads();
  float S = (rsm[0][h] + rsm[1][h]) + (rsm[2][h] + rsm[3][h]);
  wls[l][h] = e / S;
  __syncthreads();
  // wctx[h, c-pair] : thread owns c = {2*tid, 2*tid+1}, all 8 h
  float acc[16];
#pragma unroll
  for (int i = 0; i < 16; i++) acc[i] = 0.f;
#pragma unroll 4
  for (int l2 = 0; l2 < 32; l2++){
    u32 u = *(const u32*)&ctxs[l2 * 520 + 2 * tid];
    float a = bl(u), b = bh(u);
    float4 w0 = *(const float4*)&wls[l2][0];
    float4 w1 = *(const float4*)&wls[l2][4];
    acc[0] += w0.x * a; acc[1] += w0.x * b;
    acc[2] += w0.y * a; acc[3] += w0.y * b;
    acc[4] += w0.z * a; acc[5] += w0.z * b;
    acc[6] += w0.w * a; acc[7] += w0.w * b;
    acc[8] += w1.x * a; acc[9] += w1.x * b;
    acc[10]+= w1.y * a; acc[11]+= w1.y * b;
    acc[12]+= w1.z * a; acc[13]+= w1.z * b;
    acc[14]+= w1.w * a; acc[15]+= w1.w * b;
  }
  u32* wp = (u32*)(kqw + (long)blockIdx.x * 4096);
#pragma unroll
  for (int hh = 0; hh < 8; hh++)
    wp[hh * 256 + tid] = pk2(acc[hh * 2], acc[hh * 2 + 1]);
}

// K3: out[t,h,d] = sum_c wctx[t,h,c] * vwt[c, h*64+d] + v_b[h*64+d]. 32 locations/block.
__global__ __launch_bounds__(256) void k3_out(const u16* __restrict__ wctx,
                                              const u16* __restrict__ vwt,
                                              const float* __restrict__ vb,
                                              float* __restrict__ out,
                                              int base){
  __shared__ u16 wc[8][66][36];                // [h][c'][t] padded
  int tid = threadIdx.x;
  long bn0 = (long)base + blockIdx.x * 32;
  int h = tid >> 5, tg = (tid >> 3) & 3, dg = tid & 7;
  int ts = tid >> 3, hs = tid & 7;
  float acc[8][8];
#pragma unroll
  for (int i = 0; i < 8; i++)
#pragma unroll
    for (int j = 0; j < 8; j++) acc[i][j] = 0.f;
  for (int cc = 0; cc < 8; cc++){
    __syncthreads();
#pragma unroll
    for (int q8 = 0; q8 < 8; q8++){
      uint4 v = *(const uint4*)&wctx[(((long)blockIdx.x * 32 + ts) * 8 + hs) * 512 + cc * 64 + q8 * 8];
      u16 e[8] = { (u16)(v.x & 0xffff), (u16)(v.x >> 16), (u16)(v.y & 0xffff), (u16)(v.y >> 16),
                   (u16)(v.z & 0xffff), (u16)(v.z >> 16), (u16)(v.w & 0xffff), (u16)(v.w >> 16) };
#pragma unroll
      for (int j = 0; j < 8; j++) wc[hs][q8 * 8 + j][ts] = e[j];
    }
    __syncthreads();
    for (int c1 = 0; c1 < 64; c1++){
      int c = cc * 64 + c1;
      uint4 wv = *(const uint4*)&vwt[c * 512 + h * 64 + dg * 8];
      float wf[8] = { bl(wv.x), bh(wv.x), bl(wv.y), bh(wv.y), bl(wv.z), bh(wv.z), bl(wv.w), bh(wv.w) };
      uint2 t0 = *(const uint2*)&wc[h][c1][tg * 8];
      uint2 t1 = *(const uint2*)&wc[h][c1][tg * 8 + 4];
      float tf[8] = { bl(t0.x), bh(t0.x), bl(t0.y), bh(t0.y), bl(t1.x), bh(t1.x), bl(t1.y), bh(t1.y) };
#pragma unroll
      for (int i = 0; i < 8; i++)
#pragma unroll
        for (int j = 0; j < 8; j++) acc[i][j] += tf[i] * wf[j];
    }
  }
  long b = bn0 >> 12;
  long n0 = bn0 & 4095;
  float vbr[8];
#pragma unroll
  for (int j = 0; j < 8; j++) vbr[j] = vb[h * 64 + dg * 8 + j];
#pragma unroll
  for (int i = 0; i < 8; i++){
    int t = tg * 8 + i;
    float* op = out + (((b * 8 + h) * 4096 + (n0 + t)) << 6) + dg * 8;
    float4 o0, o1;
    o0.x = acc[i][0] + vbr[0]; o0.y = acc[i][1] + vbr[1];
    o0.z = acc[i][2] + vbr[2]; o0.w = acc[i][3] + vbr[3];
    o1.x = acc[i][4] + vbr[4]; o1.y = acc[i][5] + vbr[5];
    o1.z = acc[i][6] + vbr[6]; o1.w = acc[i][7] + vbr[7];
    *(float4*)op = o0;
    *((float4*)op + 1) = o1;
  }
}

extern "C" void kernel_launch(void* const* d_in, const int* in_sizes, int n_in,
                              void* d_out, int out_size, void* d_ws, size_t ws_size,
                              hipStream_t stream){
  const float* q   = (const float*)d_in[0];
  const float* ctx = (const float*)d_in[1];
  const float* kw  = (const float*)d_in[2];
  // d_in[3] = k_b : provably cancels in softmax, unused
  const float* vw  = (const float*)d_in[4];
  const float* vb  = (const float*)d_in[5];
  const float* lng = (const float*)d_in[6];
  const float* lnb = (const float*)d_in[7];
  float* out = (float*)d_out;

  u16* kwb = (u16*)d_ws;                 // 512 KB
  u16* vwt = kwb + 512 * 512;            // 512 KB
  u16* kqw = vwt + 512 * 512;            // CH * 8 KB (kq, then wctx in place)

  size_t avail = ws_size > (size_t)(1 << 20) ? ws_size - (size_t)(1 << 20) : 0;
  long CH = (long)(avail / 8192);        // 8 KB per location
  if (CH > NLOC) CH = NLOC;
  CH &= ~31L;
  if (CH < 32) CH = 32;

  hipLaunchKernelGGL(k0_prep, dim3(1024), dim3(256), 0, stream, kw, vw, kwb, vwt);
  for (long base = 0; base < NLOC; base += CH){
    long M = NLOC - base; if (M > CH) M = CH;
    hipLaunchKernelGGL(k1_lnkq, dim3(M / 32), dim3(256), 0, stream, q, lng, lnb, kwb, kqw, (int)base);
    hipLaunchKernelGGL(k2_attn, dim3(M), dim3(256), 0, stream, ctx, kqw, (int)base);
    hipLaunchKernelGGL(k3_out, dim3(M / 32), dim3(256), 0, stream, kqw, vwt, vb, out, (int)base);
  }
}